// Round 1
// baseline (463.877 us; speedup 1.0000x reference)
//
#include <hip/hip_runtime.h>

// cumprod along dim=1 of (B=32, L=4096, C=512) fp32.
// 16384 independent chains (b,c), stride C floats along scan dim.
//
// Single-pass block-chunked scan: block owns 32 channels x full L chain.
// Per 512-l chunk: 8 float4/thread in registers -> local products ->
// LDS Hillis-Steele over 64 segment products -> apply carry -> store.
// Traffic = 268 MB read + 268 MB write (single pass, ~85 us floor @6.3 TB/s).

constexpr int L  = 4096;  // scan length
constexpr int C  = 512;   // channels
constexpr int C4 = C / 4; // float4 groups per row = 128
constexpr int CG = 8;     // float4 groups per block (32 channels)
constexpr int W  = 64;    // l-segments per chunk (threads along l)
constexpr int KE = 8;     // l elements per thread per chunk
constexpr int CL = W * KE;       // 512 l per chunk
constexpr int NCHUNK = L / CL;   // 8

__device__ __forceinline__ float4 mul4(float4 a, float4 b) {
    return make_float4(a.x * b.x, a.y * b.y, a.z * b.z, a.w * b.w);
}

__global__ __launch_bounds__(CG * W, 4)  // 512 threads, 4 waves/SIMD -> 2 blocks/CU
void cumprod_kernel(const float4* __restrict__ x, float4* __restrict__ out) {
    __shared__ float4 s[W][CG + 1];  // +1 pad: break power-of-2 LDS stride

    const int tid = threadIdx.x;
    const int c4  = tid & (CG - 1);   // fast index: channel -> coalescing
    const int w   = tid >> 3;         // l-segment within chunk
    const int c4g = blockIdx.x * CG + c4;   // global float4-channel
    const int b   = blockIdx.y;

    const int base = (b * L) * C4 + c4g;    // float4 index of (b, 0, c4g); fits int32

    float4 carry = make_float4(1.f, 1.f, 1.f, 1.f);

    for (int chunk = 0; chunk < NCHUNK; ++chunk) {
        const int lbase = base + (chunk * CL + w * KE) * C4;

        // ---- load KE float4s (independent -> pipelined by compiler) ----
        float4 v[KE];
#pragma unroll
        for (int i = 0; i < KE; ++i) v[i] = x[lbase + i * C4];

        // ---- local inclusive products (register chain) ----
#pragma unroll
        for (int i = 1; i < KE; ++i) v[i] = mul4(v[i], v[i - 1]);

        // ---- scan the W=64 segment products per channel (Hillis-Steele) ----
        s[w][c4] = v[KE - 1];
        __syncthreads();
#pragma unroll
        for (int d = 1; d < W; d <<= 1) {
            float4 t;
            bool act = (w >= d);
            if (act) t = s[w - d][c4];
            __syncthreads();
            if (act) s[w][c4] = mul4(s[w][c4], t);
            __syncthreads();
        }

        // inclusive s[w] = prod of segment products 0..w
        float4 excl = carry;
        if (w > 0) excl = mul4(excl, s[w - 1][c4]);
        const float4 total = s[W - 1][c4];

        // ---- apply prefix and store ----
#pragma unroll
        for (int i = 0; i < KE; ++i) {
            out[lbase + i * C4] = mul4(excl, v[i]);
        }

        carry = mul4(carry, total);
        __syncthreads();  // protect s[] before next chunk's write
    }
}

extern "C" void kernel_launch(void* const* d_in, const int* in_sizes, int n_in,
                              void* d_out, int out_size, void* d_ws, size_t ws_size,
                              hipStream_t stream) {
    const float4* x = (const float4*)d_in[0];
    float4* out = (float4*)d_out;

    const int B = in_sizes[0] / (L * C);  // = 32

    dim3 grid(C4 / CG, B);   // (16, 32) = 512 blocks
    dim3 block(CG * W);      // 512 threads
    cumprod_kernel<<<grid, block, 0, stream>>>(x, out);
}